// Round 7
// baseline (544.767 us; speedup 1.0000x reference)
//
#include <hip/hip_runtime.h>
#include <hip/hip_bf16.h>
#include <cstddef>
#include <cstdint>
#include <math.h>

// Problem constants (Qwen2MoE attention, B=2, S=2048)
#define H_    2048
#define NH_   16
#define NKV_  4
#define HD_   128
#define S_    2048
#define B_    2
#define M_    (B_ * S_)        // 4096 rows
#define QKV_N 3072             // (NH + 2*NKV) * HD

typedef unsigned short u16;
typedef unsigned int   u32;
typedef __attribute__((ext_vector_type(8))) short s16x8;   // 8 bf16 (4 VGPRs)
typedef __attribute__((ext_vector_type(4))) float f32x4;   // MFMA C/D

__device__ inline u16 f2bf(float x) {
  __hip_bfloat16 h = __float2bfloat16(x);
  return *reinterpret_cast<u16*>(&h);
}
__device__ inline float bf2f(u16 u) {
  __hip_bfloat16 h;
  *reinterpret_cast<u16*>(&h) = u;
  return __bfloat162float(h);
}
__device__ inline u32 pack_bf2(float a, float b) {
  return (u32)f2bf(a) | ((u32)f2bf(b) << 16);
}

__device__ inline f32x4 mfma_bf16(s16x8 a, s16x8 b, f32x4 c) {
  return __builtin_amdgcn_mfma_f32_16x16x32_bf16(a, b, c, 0, 0, 0);
}

#define GLOAD(g, s)                                                  \
  __builtin_amdgcn_global_load_lds(                                  \
      (const __attribute__((address_space(1))) void*)(g),            \
      (__attribute__((address_space(3))) void*)(s), 16, 0, 0)

// ---------------------------------------------------------------------------
// split fp32 -> (hi, lo) bf16, elementwise (A matrices, [M][K] layout)
// ---------------------------------------------------------------------------
__global__ __launch_bounds__(256) void split_f32(
    const float* __restrict__ in, u16* __restrict__ hi, u16* __restrict__ lo,
    int n4) {
  int i = blockIdx.x * 256 + threadIdx.x;
  if (i >= n4) return;
  float4 v = reinterpret_cast<const float4*>(in)[i];
  float x[4] = {v.x, v.y, v.z, v.w};
  u16 hv[4], lv[4];
#pragma unroll
  for (int j = 0; j < 4; ++j) {
    hv[j] = f2bf(x[j]);
    lv[j] = f2bf(x[j] - bf2f(hv[j]));
  }
  reinterpret_cast<ushort4*>(hi)[i] = make_ushort4(hv[0], hv[1], hv[2], hv[3]);
  reinterpret_cast<ushort4*>(lo)[i] = make_ushort4(lv[0], lv[1], lv[2], lv[3]);
}

// ---------------------------------------------------------------------------
// split + transpose: W[K][N] fp32 -> Wt_hi/lo[N][K] bf16 (64x64 LDS tile)
// ---------------------------------------------------------------------------
__global__ __launch_bounds__(256) void split_transpose(
    const float* __restrict__ W, u16* __restrict__ thi, u16* __restrict__ tlo,
    int K, int N) {
  __shared__ float tile[64][65];
  const int t  = threadIdx.x;
  const int rr = t >> 4;
  const int c4 = (t & 15) * 4;
  const int k0 = blockIdx.x * 64;
  const int n0 = blockIdx.y * 64;
#pragma unroll
  for (int s = 0; s < 4; ++s) {
    int kk = rr + 16 * s;
    float4 v = *reinterpret_cast<const float4*>(&W[(size_t)(k0 + kk) * N + n0 + c4]);
    tile[kk][c4 + 0] = v.x; tile[kk][c4 + 1] = v.y;
    tile[kk][c4 + 2] = v.z; tile[kk][c4 + 3] = v.w;
  }
  __syncthreads();
#pragma unroll
  for (int s = 0; s < 4; ++s) {
    int nn = rr + 16 * s;
    u16 hv[4], lv[4];
#pragma unroll
    for (int j = 0; j < 4; ++j) {
      float x = tile[c4 + j][nn];
      hv[j] = f2bf(x);
      lv[j] = f2bf(x - bf2f(hv[j]));
    }
    size_t o = (size_t)(n0 + nn) * K + k0 + c4;
    *reinterpret_cast<ushort4*>(&thi[o]) = make_ushort4(hv[0], hv[1], hv[2], hv[3]);
    *reinterpret_cast<ushort4*>(&tlo[o]) = make_ushort4(lv[0], lv[1], lv[2], lv[3]);
  }
}

// ---------------------------------------------------------------------------
// bf16x3 split MFMA GEMM (validated r4/r6). 1D grid + 8x8 supertile remap:
// 64 consecutive blocks share 8 A-panels + 8 B-panels (~17 MB working set,
// fits aggregate L2) -> cuts the 2.7x FETCH over-read seen in r6.
// Requires (M/128)%8==0 and (N/128)%8==0 (true for 32x24 and 32x16).
// ---------------------------------------------------------------------------
__global__ __launch_bounds__(256, 2) void gemm_bf16x3(
    const u16* __restrict__ Ahi, const u16* __restrict__ Alo,
    const u16* __restrict__ Bthi, const u16* __restrict__ Btlo,
    const float* __restrict__ bias, float* __restrict__ C,
    int M, int N, int K) {
  __shared__ u16 lds[4][128][32];

  const int t  = threadIdx.x;
  const int l  = t & 63;
  const int w  = t >> 6;
  const int wr = w >> 1, wc = w & 1;

  // supertile remap
  const int bid  = blockIdx.x;
  const int nbc  = N >> 7;
  const int nstc = nbc >> 3;
  const int st   = bid >> 6;
  const int li   = bid & 63;
  const int br   = (st / nstc) * 8 + (li >> 3);
  const int bc   = (st % nstc) * 8 + (li & 7);
  const int row0 = br * 128;
  const int col0 = bc * 128;

  f32x4 acc[4][4] = {};

  const int srow  = l >> 2;
  const int gslot = (l & 3) ^ ((l >> 3) & 3);
  const int fr    = l & 15;
  const int rslot = (l >> 4) ^ (((l & 15) >> 1) & 3);

  for (int k0 = 0; k0 < K; k0 += 32) {
#pragma unroll
    for (int it = 0; it < 2; ++it) {
      const int r0 = (w + 4 * it) * 16;
      const size_t ga = (size_t)(row0 + r0 + srow) * K + k0 + gslot * 8;
      GLOAD(Ahi + ga, &lds[0][r0][0]);
      GLOAD(Alo + ga, &lds[1][r0][0]);
      const size_t gb = (size_t)(col0 + r0 + srow) * K + k0 + gslot * 8;
      GLOAD(Bthi + gb, &lds[2][r0][0]);
      GLOAD(Btlo + gb, &lds[3][r0][0]);
    }
    __syncthreads();

    s16x8 ah[4], al[4];
#pragma unroll
    for (int f = 0; f < 4; ++f) {
      const int ar = wr * 64 + f * 16 + fr;
      ah[f] = *reinterpret_cast<const s16x8*>(&lds[0][ar][rslot * 8]);
      al[f] = *reinterpret_cast<const s16x8*>(&lds[1][ar][rslot * 8]);
    }
#pragma unroll
    for (int j = 0; j < 4; ++j) {
      const int br2 = wc * 64 + j * 16 + fr;
      const s16x8 bh = *reinterpret_cast<const s16x8*>(&lds[2][br2][rslot * 8]);
      const s16x8 bl = *reinterpret_cast<const s16x8*>(&lds[3][br2][rslot * 8]);
#pragma unroll
      for (int i = 0; i < 4; ++i) {
        acc[i][j] = mfma_bf16(ah[i], bh, acc[i][j]);
        acc[i][j] = mfma_bf16(al[i], bh, acc[i][j]);
        acc[i][j] = mfma_bf16(ah[i], bl, acc[i][j]);
      }
    }
    __syncthreads();
  }

  const int rb = (l >> 4) * 4;
  const int cn = l & 15;
  float bv[4];
#pragma unroll
  for (int j = 0; j < 4; ++j)
    bv[j] = bias ? bias[col0 + wc * 64 + j * 16 + cn] : 0.f;
#pragma unroll
  for (int i = 0; i < 4; ++i)
#pragma unroll
    for (int j = 0; j < 4; ++j) {
      const int col = col0 + wc * 64 + j * 16 + cn;
#pragma unroll
      for (int r = 0; r < 4; ++r) {
        const int row = row0 + wr * 64 + i * 16 + rb + r;
        C[(size_t)row * N + col] = acc[i][j][r] + bv[j];
      }
    }
}

// ---------------------------------------------------------------------------
// prep_qk: RoPE (fp32 math) + cast to bf16.
// ---------------------------------------------------------------------------
__global__ __launch_bounds__(256) void prep_qk(
    const float* __restrict__ qkv, const int* __restrict__ positions,
    u16* __restrict__ q_bf, u16* __restrict__ k_bf) {
  int idx = blockIdx.x * 256 + threadIdx.x;
  const int total = M_ * (NH_ + NKV_) * 64;
  if (idx >= total) return;
  int j    = idx & 63;
  int head = (idx >> 6) % (NH_ + NKV_);
  int m    = idx / (64 * (NH_ + NKV_));
  int b    = m >> 11;
  int s    = m & 2047;
  float pos = (float)positions[m];
  float inv_freq = powf(1.0e6f, -(float)j * (1.0f / 64.0f));
  float ang = pos * inv_freq;
  float sn, cs;
  sincosf(ang, &sn, &cs);
  const float* src = qkv + (size_t)m * QKV_N + head * HD_ + j;
  float x1 = src[0], x2 = src[64];
  float y1 = x1 * cs - x2 * sn;
  float y2 = x2 * cs + x1 * sn;
  u16* dst;
  if (head < NH_) {
    dst = q_bf + (((size_t)(b * NH_ + head)) * S_ + s) * HD_ + j;
  } else {
    dst = k_bf + (((size_t)(b * NKV_ + (head - NH_))) * S_ + s) * HD_ + j;
  }
  dst[0]  = f2bf(y1);
  dst[64] = f2bf(y2);
}

// ---------------------------------------------------------------------------
// prep_v: V slice of qkv -> transposed bf16 vT[b][kvh][d=128][s=2048].
// ---------------------------------------------------------------------------
__global__ __launch_bounds__(256) void prep_v(
    const float* __restrict__ qkv, u16* __restrict__ vT) {
  __shared__ float tile[64][65];
  const int bk = blockIdx.x;           // b*NKV + kvh
  const int s0 = blockIdx.y * 64;
  const int d0 = blockIdx.z * 64;
  const int t  = threadIdx.x;
  const float* src = qkv + ((size_t)(bk >> 2) * S_) * QKV_N
                     + (NH_ + NKV_) * HD_ + (bk & 3) * HD_ + d0;
  {
    const int r  = t >> 2;
    const int c0 = (t & 3) * 16;
    const float* row = src + (size_t)(s0 + r) * QKV_N;
#pragma unroll
    for (int i = 0; i < 4; ++i) {
      float4 v = *reinterpret_cast<const float4*>(row + c0 + i * 4);
      tile[r][c0 + i*4 + 0] = v.x; tile[r][c0 + i*4 + 1] = v.y;
      tile[r][c0 + i*4 + 2] = v.z; tile[r][c0 + i*4 + 3] = v.w;
    }
  }
  __syncthreads();
  {
    const int d  = t >> 2;
    const int sc = (t & 3) * 16;
    u16 buf[16];
#pragma unroll
    for (int i = 0; i < 16; ++i) buf[i] = f2bf(tile[sc + i][d]);
    u16* dst = vT + ((size_t)bk * HD_ + d0 + d) * S_ + s0 + sc;
    *reinterpret_cast<ushort4*>(dst + 0)  = *reinterpret_cast<ushort4*>(&buf[0]);
    *reinterpret_cast<ushort4*>(dst + 4)  = *reinterpret_cast<ushort4*>(&buf[4]);
    *reinterpret_cast<ushort4*>(dst + 8)  = *reinterpret_cast<ushort4*>(&buf[8]);
    *reinterpret_cast<ushort4*>(dst + 12) = *reinterpret_cast<ushort4*>(&buf[12]);
  }
}

// ---------------------------------------------------------------------------
// MFMA flash attention, double-buffered K/V staging (T14/T3-minimum):
// STAGE(kt+1) issued right after the per-tile barrier, flies under the whole
// QK^T+softmax+PV of tile kt; one __syncthreads per tile (its implicit
// vmcnt(0) drain is exactly the wait we need). P write->read ordered by
// s_waitcnt lgkmcnt(0) + sched_barrier(0) (rule #18), NOT threadfence (which
// would drain the in-flight prefetch). setprio(1) around MFMA clusters (T5).
// LDS: 2*16 (K) + 2*16 (V) + 8 (P) = 72 KB -> 2 blocks/CU.
// ---------------------------------------------------------------------------
__global__ __launch_bounds__(256) void flash_mfma(
    const u16* __restrict__ q_bf, const u16* __restrict__ k_bf,
    const u16* __restrict__ vT_bf,
    u16* __restrict__ attn_hi, u16* __restrict__ attn_lo) {
  __shared__ u16 Kl[2][64 * 128];     // 2 x 16 KB
  __shared__ u16 Vl[2][128 * 64];     // 2 x 16 KB (V transposed: [d][kv])
  __shared__ u16 Pl[4 * 16 * 64];     // 8 KB (per-wave P[16 q][64 kv])

  const int t   = threadIdx.x;
  const int l   = t & 63;
  const int w   = t >> 6;
  const int bid = blockIdx.x;
  const int qt  = 31 - (bid & 31);    // heavy q-tiles dispatch first
  const int bh  = bid >> 5;
  const int h   = bh & 15;
  const int b   = bh >> 4;
  const int kvh = h >> 2;

  const int ln = l & 15;              // q-col / frag row / d-col
  const int lh = l >> 4;              // k-slot group

  const int q0 = qt * 64 + w * 16;
  const u16* Qg = q_bf  + (((size_t)(b * NH_ + h)) * S_ + q0) * HD_;
  const u16* Kg = k_bf  + ((size_t)(b * NKV_ + kvh)) * S_ * HD_;
  const u16* Vg = vT_bf + ((size_t)(b * NKV_ + kvh)) * HD_ * S_;

  // Q fragments in registers
  s16x8 qf[4];
#pragma unroll
  for (int c = 0; c < 4; ++c)
    qf[c] = *reinterpret_cast<const s16x8*>(Qg + (size_t)ln * HD_ + c * 32 + lh * 8);

  f32x4 o[8] = {};
  float mrow = -INFINITY, lrow = 0.f;

  const float scale = 0.08838834764831845f;  // 128^-0.5
  const int nkt = qt + 1;
  u32* const Pw = reinterpret_cast<u32*>(&Pl[0]) + w * 512 + ln * 32;
  const u32 qm = (u32)((ln & 7) << 2);
  const int vr = l >> 3;              // V-stage row-within-seg
  const int vs = l & 7;               // V-stage slot

  // ---- prologue: stage tile 0 into buffer 0 ----
#pragma unroll
  for (int i = 0; i < 4; ++i) {
    const int seg = w + 4 * i;
    const int r   = seg * 4 + lh;
    GLOAD(Kg + (size_t)r * HD_ + ((ln ^ (r & 7)) * 8), &Kl[0][seg * 512]);
  }
#pragma unroll
  for (int i = 0; i < 4; ++i) {
    const int seg = w + 4 * i;
    const int d   = seg * 8 + vr;
    GLOAD(Vg + (size_t)d * S_ + ((vs ^ (d & 7)) * 8), &Vl[0][seg * 512]);
  }

  int cur = 0;
  for (int kt = 0; kt < nkt; ++kt) {
    __syncthreads();  // drains vmcnt: buf[cur] staged; prior-tile reads done

    // prefetch next tile into the other buffer (flies under this tile's math)
    if (kt + 1 < nkt) {
      const int kv1 = (kt + 1) * 64;
#pragma unroll
      for (int i = 0; i < 4; ++i) {
        const int seg = w + 4 * i;
        const int r   = seg * 4 + lh;
        GLOAD(Kg + (size_t)(kv1 + r) * HD_ + ((ln ^ (r & 7)) * 8),
              &Kl[cur ^ 1][seg * 512]);
      }
#pragma unroll
      for (int i = 0; i < 4; ++i) {
        const int seg = w + 4 * i;
        const int d   = seg * 8 + vr;
        GLOAD(Vg + (size_t)d * S_ + kv1 + ((vs ^ (d & 7)) * 8),
              &Vl[cur ^ 1][seg * 512]);
      }
    }

    const u16* Kc = &Kl[cur][0];
    const u16* Vc = &Vl[cur][0];
    const int kv0 = kt * 64;

    // ---- S^T[kv][q] = K · Q^T : 16 MFMAs ----
    f32x4 sa[4] = {};
    __builtin_amdgcn_s_setprio(1);
#pragma unroll
    for (int a = 0; a < 4; ++a) {
      const int row = a * 16 + ln;
#pragma unroll
      for (int c = 0; c < 4; ++c) {
        const int slot = (c * 4 + lh) ^ (row & 7);
        const s16x8 kf = *reinterpret_cast<const s16x8*>(&Kc[row * 128 + slot * 8]);
        sa[a] = mfma_bf16(kf, qf[c], sa[a]);
      }
    }
    __builtin_amdgcn_s_setprio(0);

    // ---- scale + causal mask + online softmax (per q-row = ln) ----
    float p[16];
    float lm = -INFINITY;
#pragma unroll
    for (int a = 0; a < 4; ++a)
#pragma unroll
      for (int r = 0; r < 4; ++r) {
        float sv = sa[a][r] * scale;
        const int kvg = kv0 + a * 16 + lh * 4 + r;
        if (kt == qt && kvg > q0 + ln) sv = -INFINITY;
        p[a * 4 + r] = sv;
        lm = fmaxf(lm, sv);
      }
    lm = fmaxf(lm, __shfl_xor(lm, 16, 64));
    lm = fmaxf(lm, __shfl_xor(lm, 32, 64));
    const float mnew  = fmaxf(mrow, lm);
    const float alpha = __expf(mrow - mnew);
    mrow = mnew;
    float rs = 0.f;
#pragma unroll
    for (int i = 0; i < 16; ++i) {
      p[i] = __expf(p[i] - mnew);
      rs += p[i];
    }
    rs += __shfl_xor(rs, 16, 64);
    rs += __shfl_xor(rs, 32, 64);
    lrow = lrow * alpha + rs;

    // ---- write P (bf16) to per-wave LDS, swizzled ----
#pragma unroll
    for (int a = 0; a < 4; ++a) {
      const u32 u0 = (u32)(a * 8 + lh * 2);
      Pw[u0 ^ qm]       = pack_bf2(p[a * 4 + 0], p[a * 4 + 1]);
      Pw[(u0 + 1) ^ qm] = pack_bf2(p[a * 4 + 2], p[a * 4 + 3]);
    }

    // ---- rescale O (overlaps P-write latency) ----
    float af[4];
#pragma unroll
    for (int r = 0; r < 4; ++r)
      af[r] = __shfl(alpha, (l & 48) | (lh * 4 + r), 64);
#pragma unroll
    for (int dt = 0; dt < 8; ++dt)
#pragma unroll
      for (int r = 0; r < 4; ++r) o[dt][r] *= af[r];

    // order P writes before cross-lane P reads (keeps prefetch in flight —
    // lgkmcnt does NOT wait global_load_lds, which counts in vmcnt)
    asm volatile("s_waitcnt lgkmcnt(0)" ::: "memory");
    __builtin_amdgcn_sched_barrier(0);

    // ---- PV: O[16 q][128 d] += P[16][64] · V[64][128] : 16 MFMAs ----
    __builtin_amdgcn_s_setprio(1);
#pragma unroll
    for (int kc = 0; kc < 2; ++kc) {
      const u32 ub = ((u32)(kc * 16 + lh * 4)) ^ qm;
      const s16x8 pf = *reinterpret_cast<const s16x8*>(Pw + ub);
#pragma unroll
      for (int dt = 0; dt < 8; ++dt) {
        const int d    = dt * 16 + ln;
        const int slot = (kc * 4 + lh) ^ (d & 7);
        const s16x8 vf = *reinterpret_cast<const s16x8*>(&Vc[d * 64 + slot * 8]);
        o[dt] = mfma_bf16(pf, vf, o[dt]);
      }
    }
    __builtin_amdgcn_s_setprio(0);

    cur ^= 1;
  }

  // ---- epilogue: O/l, write split hi/lo bf16 attn[b, q, h*128 + d] ----
  float li[4];
#pragma unroll
  for (int r = 0; r < 4; ++r)
    li[r] = 1.f / __shfl(lrow, (l & 48) | (lh * 4 + r), 64);
#pragma unroll
  for (int r = 0; r < 4; ++r) {
    const size_t rowg = (size_t)(b * S_) + q0 + lh * 4 + r;
    u16* oh = attn_hi + rowg * (NH_ * HD_) + h * HD_;
    u16* ol = attn_lo + rowg * (NH_ * HD_) + h * HD_;
#pragma unroll
    for (int dt = 0; dt < 8; ++dt) {
      const float v = o[dt][r] * li[r];
      const u16 hv = f2bf(v);
      oh[dt * 16 + ln] = hv;
      ol[dt * 16 + ln] = f2bf(v - bf2f(hv));
    }
  }
}

// ---------------------------------------------------------------------------
extern "C" void kernel_launch(void* const* d_in, const int* in_sizes, int n_in,
                              void* d_out, int out_size, void* d_ws, size_t ws_size,
                              hipStream_t stream) {
  (void)in_sizes; (void)n_in; (void)out_size; (void)ws_size;
  const int*   positions = (const int*)d_in[0];
  const float* hidden    = (const float*)d_in[1];
  const float* Wqkv      = (const float*)d_in[2];
  const float* bqkv      = (const float*)d_in[3];
  const float* Wo        = (const float*)d_in[4];
  float* out = (float*)d_out;

  // workspace layout (152 MB total — validated r4/r6 budget)
  char* p = (char*)d_ws;
  float* qkv     = (float*)p;  p += (size_t)M_ * QKV_N * 4;   // 48 MB
  u16*   attn_hi = (u16*)p;    p += (size_t)M_ * H_ * 2;      // 16 MB
  u16*   attn_lo = (u16*)p;    p += (size_t)M_ * H_ * 2;      // 16 MB
  u16*   hid_hi  = (u16*)p;    p += (size_t)M_ * H_ * 2;      // 16 MB
  u16*   hid_lo  = (u16*)p;    p += (size_t)M_ * H_ * 2;      // 16 MB
  u16*   wq_hi   = (u16*)p;    p += (size_t)QKV_N * H_ * 2;   // 12 MB
  u16*   wq_lo   = (u16*)p;    p += (size_t)QKV_N * H_ * 2;   // 12 MB
  u16*   wo_hi   = (u16*)p;    p += (size_t)H_ * H_ * 2;      // 8 MB
  u16*   wo_lo   = (u16*)p;    p += (size_t)H_ * H_ * 2;      // 8 MB

  // overlays (dead-after-gemm1 regions)
  u16* q_bf = hid_hi;                                   // 16 MB
  u16* k_bf = hid_lo;                                   // 4 MB
  u16* vT   = hid_lo + (size_t)B_ * NKV_ * S_ * HD_;    // 4 MB

  split_f32<<<(M_ * H_ / 4 + 255) / 256, 256, 0, stream>>>(
      hidden, hid_hi, hid_lo, M_ * H_ / 4);
  split_transpose<<<dim3(H_ / 64, QKV_N / 64), 256, 0, stream>>>(
      Wqkv, wq_hi, wq_lo, H_, QKV_N);
  split_transpose<<<dim3(H_ / 64, H_ / 64), 256, 0, stream>>>(
      Wo, wo_hi, wo_lo, H_, H_);

  gemm_bf16x3<<<(M_ / 128) * (QKV_N / 128), 256, 0, stream>>>(
      hid_hi, hid_lo, wq_hi, wq_lo, bqkv, qkv, M_, QKV_N, H_);

  const int qk_total = M_ * (NH_ + NKV_) * 64;
  prep_qk<<<(qk_total + 255) / 256, 256, 0, stream>>>(qkv, positions, q_bf, k_bf);
  prep_v<<<dim3(B_ * NKV_, S_ / 64, HD_ / 64), 256, 0, stream>>>(qkv, vT);

  flash_mfma<<<B_ * NH_ * (S_ / 64), 256, 0, stream>>>(
      q_bf, k_bf, vT, attn_hi, attn_lo);

  gemm_bf16x3<<<(M_ / 128) * (H_ / 128), 256, 0, stream>>>(
      attn_hi, attn_lo, wo_hi, wo_lo, nullptr, out, M_, H_, H_);
}